// Round 7
// baseline (1021.995 us; speedup 1.0000x reference)
//
#include <hip/hip_runtime.h>
#include <hip/hip_bf16.h>
#include <stdint.h>

#define DEVINL __device__ __forceinline__

typedef __bf16 bf16x8 __attribute__((ext_vector_type(8)));
typedef float  f32x4  __attribute__((ext_vector_type(4)));
typedef unsigned int uint2v __attribute__((ext_vector_type(2)));
typedef unsigned int uint4v __attribute__((ext_vector_type(4)));
typedef unsigned short ushort_t;

#define VSZ   50257
#define EDIM  512
#define HDIM  1024
#define BATCH 64
#define SEQ   512

// ---------------- helpers ----------------

DEVINL f32x4 MF(bf16x8 a, bf16x8 b, f32x4 c) {
  return __builtin_amdgcn_mfma_f32_16x16x32_bf16(a, b, c, 0, 0, 0);
}

// LDS tiles are [rows][64] bf16 with XOR swizzle on the k index (bytes: ^((row&7)<<4))
// so ds_read_b128 fragment reads are ~2-way max (free).
DEVINL bf16x8 ldfrag(const short* buf, int row, int k) {
  uint4v t = *(const uint4v*)&buf[row * 64 + (k ^ ((row & 7) << 3))];
  return __builtin_bit_cast(bf16x8, t);
}

// f32 -> (bf16 hi RZ, bf16 lo RZ) split of 4 elems, packed as 2x u32 each.
// hi = top 16 bits of f32 (exact subtraction), lo = top 16 bits of (f - hi).
// Effective input precision ~2^-16 relative: plenty for the 0.0297 threshold.
DEVINL void split4(f32x4 w, uint2v& hv, uint2v& lv) {
  unsigned u0 = __float_as_uint(w.x), u1 = __float_as_uint(w.y);
  unsigned u2 = __float_as_uint(w.z), u3 = __float_as_uint(w.w);
  unsigned h0 = u0 & 0xFFFF0000u, h1 = u1 & 0xFFFF0000u;
  unsigned h2 = u2 & 0xFFFF0000u, h3 = u3 & 0xFFFF0000u;
  hv.x = (h0 >> 16) | h1;
  hv.y = (h2 >> 16) | h3;
  float l0 = w.x - __uint_as_float(h0);
  float l1 = w.y - __uint_as_float(h1);
  float l2 = w.z - __uint_as_float(h2);
  float l3 = w.w - __uint_as_float(h3);
  lv.x = (__float_as_uint(l0) >> 16) | (__float_as_uint(l1) & 0xFFFF0000u);
  lv.y = (__float_as_uint(l2) >> 16) | (__float_as_uint(l3) & 0xFFFF0000u);
}

// f32x4 -> bf16 (round-to-nearest-even-ish via +0x7FFF+lsb trick), packed 2x u32
DEVINL uint2v packhi4_rn(f32x4 w) {
  unsigned u0 = __float_as_uint(w.x), u1 = __float_as_uint(w.y);
  unsigned u2 = __float_as_uint(w.z), u3 = __float_as_uint(w.w);
  unsigned r0 = u0 + 0x7FFFu + ((u0 >> 16) & 1u);
  unsigned r1 = u1 + 0x7FFFu + ((u1 >> 16) & 1u);
  unsigned r2 = u2 + 0x7FFFu + ((u2 >> 16) & 1u);
  unsigned r3 = u3 + 0x7FFFu + ((u3 >> 16) & 1u);
  uint2v o;
  o.x = (r0 >> 16) | (r1 & 0xFFFF0000u);
  o.y = (r2 >> 16) | (r3 & 0xFFFF0000u);
  return o;
}

DEVINL float fast_tanh(float s) {
  // tanh(s) = 1 - 2/(e^{2s}+1); exact +-1 saturation at inf/0 underflow.
  float e2 = __expf(2.0f * s);
  return 1.0f - 2.0f * __builtin_amdgcn_rcpf(e2 + 1.0f);
}

// ---------------- kernel 1: split W into bf16 hi/lo ----------------
__global__ __launch_bounds__(256) void prep_w_kernel(const float* __restrict__ W,
                                                     ushort_t* __restrict__ Whi,
                                                     ushort_t* __restrict__ Wlo) {
  int idx4 = blockIdx.x * 256 + threadIdx.x;  // 262144 float4s = 1M elems
  f32x4 w = *(const f32x4*)&W[(size_t)idx4 * 4];
  uint2v hv, lv;
  split4(w, hv, lv);
  ((uint2v*)Whi)[idx4] = hv;
  ((uint2v*)Wlo)[idx4] = lv;
}

// ---------------- kernel 2: Uh[b][i] = sum_j U[i][j]*hidden[b][j] (f32) ----------------
// One wave per i; lanes split j; 64 per-lane accumulators (one per b); butterfly reduce.
__global__ __launch_bounds__(256) void uh_kernel(const float* __restrict__ U,
                                                 const float* __restrict__ hidden,
                                                 float* __restrict__ Uh) {
  int wid = threadIdx.x >> 6, lane = threadIdx.x & 63;
  int i = blockIdx.x * 4 + wid;  // 256 blocks -> i in [0,1024)
  const float* Urow = U + (size_t)i * HDIM;
  float acc[64];
#pragma unroll
  for (int b = 0; b < 64; ++b) acc[b] = 0.0f;
  for (int t = 0; t < HDIM / 64; ++t) {
    float w = Urow[t * 64 + lane];
#pragma unroll
    for (int b = 0; b < 64; ++b)
      acc[b] += w * hidden[(size_t)b * HDIM + t * 64 + lane];
  }
#pragma unroll
  for (int mask = 1; mask <= 32; mask <<= 1)
#pragma unroll
    for (int b = 0; b < 64; ++b) acc[b] += __shfl_xor(acc[b], mask, 64);
  if (lane == 0) {
#pragma unroll
    for (int b = 0; b < 64; ++b) Uh[(size_t)b * HDIM + i] = acc[b];
  }
}

// ---------------- kernel 3: fused e = v . tanh(W@enc + Uh) via split-bf16 MFMA ----------------
// grid (8, 256): x = i-chunk (128 cols of H), y = row tile (128 of B*S). 4 waves.
// 3-pass MFMA: hi*hi + hi*lo + lo*hi. Epilogue folds tanh + v-dot; emits e_parts[8][32768].
__global__ __launch_bounds__(256) void e_kernel(const float* __restrict__ enc,
                                                const ushort_t* __restrict__ Whi,
                                                const ushort_t* __restrict__ Wlo,
                                                const float* __restrict__ Uh,
                                                const float* __restrict__ v,
                                                float* __restrict__ e_parts) {
  __shared__ short Ahi[128 * 64], Alo[128 * 64], Bhi[128 * 64], Blo[128 * 64];
  __shared__ float ewave[2][2][64];

  const int t = threadIdx.x;
  const int i0 = blockIdx.x * 128;   // col chunk in H
  const int bs0 = blockIdx.y * 128;  // row tile in B*S
  const int wid = t >> 6, lane = t & 63, r = lane & 15, g = lane >> 4;
  const int wr = wid >> 1, wc = wid & 1;

  f32x4 z4 = {0.f, 0.f, 0.f, 0.f};
  f32x4 acc[4][4];
#pragma unroll
  for (int m = 0; m < 4; ++m)
#pragma unroll
    for (int n = 0; n < 4; ++n) acc[m][n] = z4;

  for (int kt = 0; kt < 16; ++kt) {
    __syncthreads();
    // stage A (enc rows, f32 -> hi/lo bf16), 128x64
#pragma unroll
    for (int rep = 0; rep < 8; ++rep) {
      int p = rep * 256 + t;
      int row = p >> 4, c = p & 15;
      f32x4 w = *(const f32x4*)&enc[(size_t)(bs0 + row) * HDIM + kt * 64 + c * 4];
      uint2v hv, lv;
      split4(w, hv, lv);
      int idx = row * 64 + ((c * 4) ^ ((row & 7) << 3));
      *(uint2v*)&Ahi[idx] = hv;
      *(uint2v*)&Alo[idx] = lv;
    }
    // stage B (precomputed W hi/lo bf16), 128x64
#pragma unroll
    for (int rep = 0; rep < 4; ++rep) {
      int p = rep * 256 + t;
      int row = p >> 3, c = p & 7;
      int idx = row * 64 + ((c * 8) ^ ((row & 7) << 3));
      *(uint4v*)&Bhi[idx] = *(const uint4v*)&Whi[(size_t)(i0 + row) * HDIM + kt * 64 + c * 8];
      *(uint4v*)&Blo[idx] = *(const uint4v*)&Wlo[(size_t)(i0 + row) * HDIM + kt * 64 + c * 8];
    }
    __syncthreads();
#pragma unroll
    for (int ks = 0; ks < 2; ++ks) {
      int k = ks * 32 + g * 8;
      bf16x8 ah[4], al[4], bh[4], bl[4];
#pragma unroll
      for (int m = 0; m < 4; ++m) {
        int arow = wr * 64 + m * 16 + r;
        ah[m] = ldfrag(Ahi, arow, k);
        al[m] = ldfrag(Alo, arow, k);
        int brow = wc * 64 + m * 16 + r;
        bh[m] = ldfrag(Bhi, brow, k);
        bl[m] = ldfrag(Blo, brow, k);
      }
#pragma unroll
      for (int m = 0; m < 4; ++m)
#pragma unroll
        for (int n = 0; n < 4; ++n) {
          acc[m][n] = MF(ah[m], bh[n], acc[m][n]);
          acc[m][n] = MF(ah[m], bl[n], acc[m][n]);
          acc[m][n] = MF(al[m], bh[n], acc[m][n]);
        }
    }
  }

  // epilogue: e contribution = sum over this block's 128 cols of v[i]*tanh(Wh+Uh)
  const int b = bs0 >> 9;  // 128-row tile lies within one batch row (512 | tiles)
  float uhv[4], vv[4];
#pragma unroll
  for (int n = 0; n < 4; ++n) {
    int col = i0 + wc * 64 + n * 16 + r;
    uhv[n] = Uh[(size_t)b * HDIM + col];
    vv[n] = v[col];
  }
  float esum[16];
#pragma unroll
  for (int q = 0; q < 16; ++q) esum[q] = 0.0f;
#pragma unroll
  for (int m = 0; m < 4; ++m)
#pragma unroll
    for (int n = 0; n < 4; ++n)
#pragma unroll
      for (int j = 0; j < 4; ++j) {
        float s = acc[m][n][j] + uhv[n];
        esum[m * 4 + j] += fast_tanh(s) * vv[n];
      }
  // reduce across the 16 lanes of each quarter (cols), C layout: col = lane&15
#pragma unroll
  for (int mask = 1; mask <= 8; mask <<= 1)
#pragma unroll
    for (int q = 0; q < 16; ++q) esum[q] += __shfl_xor(esum[q], mask, 64);
  if (r == 0) {
#pragma unroll
    for (int m = 0; m < 4; ++m)
#pragma unroll
      for (int j = 0; j < 4; ++j)
        ewave[wr][wc][m * 16 + g * 4 + j] = esum[m * 4 + j];
  }
  __syncthreads();
  if (t < 128) {
    int w2 = t >> 6, rr = t & 63;
    e_parts[(size_t)blockIdx.x * 32768 + bs0 + w2 * 64 + rr] =
        ewave[w2][0][rr] + ewave[w2][1][rr];
  }
}

// ---------------- kernel 4: softmax over S per b ----------------
__global__ __launch_bounds__(256) void softmax_kernel(const float* __restrict__ e_parts,
                                                      float* __restrict__ alpha) {
  __shared__ float red[256];
  int b = blockIdx.x, t = threadIdx.x;
  float ev0 = 0.f, ev1 = 0.f;
#pragma unroll
  for (int nc = 0; nc < 8; ++nc) {
    ev0 += e_parts[(size_t)nc * 32768 + b * SEQ + t];
    ev1 += e_parts[(size_t)nc * 32768 + b * SEQ + t + 256];
  }
  red[t] = fmaxf(ev0, ev1);
  __syncthreads();
  for (int off = 128; off > 0; off >>= 1) {
    if (t < off) red[t] = fmaxf(red[t], red[t + off]);
    __syncthreads();
  }
  float mx = red[0];
  __syncthreads();
  float x0 = __expf(ev0 - mx), x1 = __expf(ev1 - mx);
  red[t] = x0 + x1;
  __syncthreads();
  for (int off = 128; off > 0; off >>= 1) {
    if (t < off) red[t] += red[t + off];
    __syncthreads();
  }
  float inv = 1.0f / red[0];
  alpha[b * SEQ + t] = x0 * inv;
  alpha[b * SEQ + t + 256] = x1 * inv;
}

// ---------------- kernel 5: context partials over s-quarters ----------------
__global__ __launch_bounds__(256) void ctx_kernel(const float* __restrict__ alpha,
                                                  const float* __restrict__ enc,
                                                  float* __restrict__ ctx_parts) {
  int b = blockIdx.x, q = blockIdx.y, t = threadIdx.x;
  f32x4 acc = {0.f, 0.f, 0.f, 0.f};
  for (int s = q * 128; s < q * 128 + 128; ++s) {
    float a = alpha[b * SEQ + s];
    f32x4 ev = *(const f32x4*)&enc[((size_t)b * SEQ + s) * HDIM + t * 4];
    acc.x += a * ev.x; acc.y += a * ev.y; acc.z += a * ev.z; acc.w += a * ev.w;
  }
  *(f32x4*)&ctx_parts[((size_t)q * BATCH + b) * HDIM + t * 4] = acc;
}

__global__ __launch_bounds__(256) void ctx_reduce_kernel(const float* __restrict__ ctx_parts,
                                                         float* __restrict__ ctx) {
  int idx = blockIdx.x * 256 + threadIdx.x;  // 16384 float4s = 65536 elems
  const f32x4* p = (const f32x4*)ctx_parts;
  f32x4 s0 = p[idx];
  f32x4 s1 = p[idx + 16384];
  f32x4 s2 = p[idx + 32768];
  f32x4 s3 = p[idx + 49152];
  f32x4 r;
  r.x = s0.x + s1.x + s2.x + s3.x;
  r.y = s0.y + s1.y + s2.y + s3.y;
  r.z = s0.z + s1.z + s2.z + s3.z;
  r.w = s0.w + s1.w + s2.w + s3.w;
  ((f32x4*)ctx)[idx] = r;
}

// ---------------- kernel 6: RNN step h = tanh(x@Wih^T + ctx@Whh^T + biases) ----------------
// wave per i; lanes split j; 64 per-lane accumulators (per b); butterfly reduce.
__global__ __launch_bounds__(256) void rnn_kernel(const int* __restrict__ inp,
                                                  const float* __restrict__ emb,
                                                  const float* __restrict__ Wih,
                                                  const float* __restrict__ Whh,
                                                  const float* __restrict__ bih,
                                                  const float* __restrict__ bhh,
                                                  const float* __restrict__ ctx,
                                                  float* __restrict__ h_out,
                                                  ushort_t* __restrict__ h_bf16) {
  int wid = threadIdx.x >> 6, lane = threadIdx.x & 63;
  int i = blockIdx.x * 4 + wid;
  float acc[64];
#pragma unroll
  for (int b = 0; b < 64; ++b) acc[b] = 0.0f;
  const float* w1 = Wih + (size_t)i * EDIM;
  for (int t = 0; t < EDIM / 64; ++t) {
    float w = w1[t * 64 + lane];
#pragma unroll
    for (int b = 0; b < 64; ++b)
      acc[b] += w * emb[(size_t)inp[b] * EDIM + t * 64 + lane];
  }
  const float* w2 = Whh + (size_t)i * HDIM;
  for (int t = 0; t < HDIM / 64; ++t) {
    float w = w2[t * 64 + lane];
#pragma unroll
    for (int b = 0; b < 64; ++b)
      acc[b] += w * ctx[(size_t)b * HDIM + t * 64 + lane];
  }
#pragma unroll
  for (int mask = 1; mask <= 32; mask <<= 1)
#pragma unroll
    for (int b = 0; b < 64; ++b) acc[b] += __shfl_xor(acc[b], mask, 64);
  if (lane == 0) {
    float bias = bih[i] + bhh[i];
#pragma unroll
    for (int b = 0; b < 64; ++b) {
      float hv = fast_tanh(acc[b] + bias);
      h_out[(size_t)b * HDIM + i] = hv;
      unsigned u = __float_as_uint(hv);
      h_bf16[(size_t)b * HDIM + i] = (ushort_t)((u + 0x7FFFu + ((u >> 16) & 1u)) >> 16);
    }
  }
}

// ---------------- kernel 7: logits = h @ outW^T + outb (single-pass bf16 MFMA) ----------------
__global__ __launch_bounds__(256) void logits_kernel(const ushort_t* __restrict__ hbf,
                                                     const float* __restrict__ outW,
                                                     const float* __restrict__ outb,
                                                     float* __restrict__ out) {
  __shared__ short As[64 * 64];   // h tile
  __shared__ short Bs[128 * 64];  // outW tile (converted)
  const int t = threadIdx.x;
  const int n0 = blockIdx.x * 128;
  const int wid = t >> 6, lane = t & 63, r = lane & 15, g = lane >> 4;

  f32x4 z4 = {0.f, 0.f, 0.f, 0.f};
  f32x4 acc[4][2];
#pragma unroll
  for (int m = 0; m < 4; ++m) {
    acc[m][0] = z4;
    acc[m][1] = z4;
  }

  for (int kt = 0; kt < 16; ++kt) {
    __syncthreads();
#pragma unroll
    for (int rep = 0; rep < 2; ++rep) {
      int p = rep * 256 + t;
      int row = p >> 3, c = p & 7;
      *(uint4v*)&As[row * 64 + ((c * 8) ^ ((row & 7) << 3))] =
          *(const uint4v*)&hbf[(size_t)row * HDIM + kt * 64 + c * 8];
    }
#pragma unroll
    for (int rep = 0; rep < 8; ++rep) {
      int p = rep * 256 + t;
      int row = p >> 4, c = p & 15;
      int gr = n0 + row;
      f32x4 wv = z4;
      if (gr < VSZ) wv = *(const f32x4*)&outW[(size_t)gr * HDIM + kt * 64 + c * 4];
      *(uint2v*)&Bs[row * 64 + ((c * 4) ^ ((row & 7) << 3))] = packhi4_rn(wv);
    }
    __syncthreads();
#pragma unroll
    for (int ks = 0; ks < 2; ++ks) {
      int k = ks * 32 + g * 8;
      bf16x8 a[4], bb[2];
#pragma unroll
      for (int m = 0; m < 4; ++m) a[m] = ldfrag(As, m * 16 + r, k);
#pragma unroll
      for (int n = 0; n < 2; ++n) bb[n] = ldfrag(Bs, wid * 32 + n * 16 + r, k);
#pragma unroll
      for (int m = 0; m < 4; ++m)
#pragma unroll
        for (int n = 0; n < 2; ++n) acc[m][n] = MF(a[m], bb[n], acc[m][n]);
    }
  }
#pragma unroll
  for (int n = 0; n < 2; ++n) {
    int col = n0 + wid * 32 + n * 16 + r;
    if (col < VSZ) {
      float ob = outb[col];
#pragma unroll
      for (int m = 0; m < 4; ++m)
#pragma unroll
        for (int j = 0; j < 4; ++j) {
          int row = m * 16 + g * 4 + j;  // batch index
          out[(size_t)row * VSZ + col] = acc[m][n][j] + ob;
        }
    }
  }
}

// ---------------- launch ----------------
extern "C" void kernel_launch(void* const* d_in, const int* in_sizes, int n_in,
                              void* d_out, int out_size, void* d_ws, size_t ws_size,
                              hipStream_t stream) {
  const int* inp = (const int*)d_in[0];
  const float* hidden = (const float*)d_in[1];
  const float* enc = (const float*)d_in[2];
  const float* emb = (const float*)d_in[3];
  const float* W = (const float*)d_in[4];
  const float* U = (const float*)d_in[5];
  const float* v = (const float*)d_in[6];
  const float* Wih = (const float*)d_in[7];
  const float* Whh = (const float*)d_in[8];
  const float* bih = (const float*)d_in[9];
  const float* bhh = (const float*)d_in[10];
  const float* outW = (const float*)d_in[11];
  const float* outb = (const float*)d_in[12];
  float* out = (float*)d_out;

  char* ws = (char*)d_ws;
  ushort_t* Whi = (ushort_t*)(ws + 0);              // 2 MB
  ushort_t* Wlo = (ushort_t*)(ws + 2097152);        // 2 MB
  float* Uh = (float*)(ws + 4194304);               // 256 KB
  float* e_parts = (float*)(ws + 4456448);          // 1 MB (8 x 32768)
  float* alpha = (float*)(ws + 5505024);            // 128 KB
  float* ctx_parts = (float*)(ws + 5636096);        // 1 MB (4 x 64 x 1024)
  float* ctx = (float*)(ws + 6684672);              // 256 KB
  ushort_t* hbf = (ushort_t*)(ws + 6946816);        // 128 KB
  // total ws usage: ~7.08 MB

  prep_w_kernel<<<1024, 256, 0, stream>>>(W, Whi, Wlo);
  uh_kernel<<<256, 256, 0, stream>>>(U, hidden, Uh);
  e_kernel<<<dim3(8, 256), 256, 0, stream>>>(enc, Whi, Wlo, Uh, v, e_parts);
  softmax_kernel<<<64, 256, 0, stream>>>(e_parts, alpha);
  ctx_kernel<<<dim3(64, 4), 256, 0, stream>>>(alpha, enc, ctx_parts);
  ctx_reduce_kernel<<<64, 256, 0, stream>>>(ctx_parts, ctx);
  rnn_kernel<<<256, 256, 0, stream>>>(inp, emb, Wih, Whh, bih, bhh, ctx,
                                      out + (size_t)BATCH * VSZ, hbf);
  logits_kernel<<<(VSZ + 127) / 128, 256, 0, stream>>>(hbf, outW, outb, out);
}

// Round 8
// 832.666 us; speedup vs baseline: 1.2274x; 1.2274x over previous
//
#include <hip/hip_runtime.h>
#include <hip/hip_bf16.h>
#include <stdint.h>

#define DEVINL __device__ __forceinline__

typedef __bf16 bf16x8 __attribute__((ext_vector_type(8)));
typedef float  f32x4  __attribute__((ext_vector_type(4)));
typedef unsigned int uint2v __attribute__((ext_vector_type(2)));
typedef unsigned int uint4v __attribute__((ext_vector_type(4)));
typedef unsigned short ushort_t;

#define VSZ   50257
#define EDIM  512
#define HDIM  1024
#define BATCH 64
#define SEQ   512

// ---------------- helpers ----------------

DEVINL f32x4 MF(bf16x8 a, bf16x8 b, f32x4 c) {
  return __builtin_amdgcn_mfma_f32_16x16x32_bf16(a, b, c, 0, 0, 0);
}

// 128x32 bf16 tiles padded to 40 shorts/row (80 B): 8-row bank cycle -> <=2-way.
DEVINL bf16x8 ldfrag40(const short* buf, int row, int k) {
  uint4v t = *(const uint4v*)&buf[row * 40 + k];
  return __builtin_bit_cast(bf16x8, t);
}

// 64-wide swizzled tiles (logits): byte ^((row&7)<<4) -> conflict-free 8-row cycle.
DEVINL bf16x8 ldfrag(const short* buf, int row, int k) {
  uint4v t = *(const uint4v*)&buf[row * 64 + (k ^ ((row & 7) << 3))];
  return __builtin_bit_cast(bf16x8, t);
}

// f32 -> (bf16 hi RZ, bf16 lo RZ) split of 4 elems, packed as 2x u32 each.
DEVINL void split4(f32x4 w, uint2v& hv, uint2v& lv) {
  unsigned u0 = __float_as_uint(w.x), u1 = __float_as_uint(w.y);
  unsigned u2 = __float_as_uint(w.z), u3 = __float_as_uint(w.w);
  unsigned h0 = u0 & 0xFFFF0000u, h1 = u1 & 0xFFFF0000u;
  unsigned h2 = u2 & 0xFFFF0000u, h3 = u3 & 0xFFFF0000u;
  hv.x = (h0 >> 16) | h1;
  hv.y = (h2 >> 16) | h3;
  float l0 = w.x - __uint_as_float(h0);
  float l1 = w.y - __uint_as_float(h1);
  float l2 = w.z - __uint_as_float(h2);
  float l3 = w.w - __uint_as_float(h3);
  lv.x = (__float_as_uint(l0) >> 16) | (__float_as_uint(l1) & 0xFFFF0000u);
  lv.y = (__float_as_uint(l2) >> 16) | (__float_as_uint(l3) & 0xFFFF0000u);
}

// f32x4 -> bf16 rne-ish, packed 2x u32
DEVINL uint2v packhi4_rn(f32x4 w) {
  unsigned u0 = __float_as_uint(w.x), u1 = __float_as_uint(w.y);
  unsigned u2 = __float_as_uint(w.z), u3 = __float_as_uint(w.w);
  unsigned r0 = u0 + 0x7FFFu + ((u0 >> 16) & 1u);
  unsigned r1 = u1 + 0x7FFFu + ((u1 >> 16) & 1u);
  unsigned r2 = u2 + 0x7FFFu + ((u2 >> 16) & 1u);
  unsigned r3 = u3 + 0x7FFFu + ((u3 >> 16) & 1u);
  uint2v o;
  o.x = (r0 >> 16) | (r1 & 0xFFFF0000u);
  o.y = (r2 >> 16) | (r3 & 0xFFFF0000u);
  return o;
}

DEVINL float fast_tanh(float s) {
  float e2 = __expf(2.0f * s);
  return 1.0f - 2.0f * __builtin_amdgcn_rcpf(e2 + 1.0f);
}

// ---------------- kernel 1: split W into bf16 hi/lo ----------------
__global__ __launch_bounds__(256) void prep_w_kernel(const float* __restrict__ W,
                                                     ushort_t* __restrict__ Whi,
                                                     ushort_t* __restrict__ Wlo) {
  int idx4 = blockIdx.x * 256 + threadIdx.x;
  f32x4 w = *(const f32x4*)&W[(size_t)idx4 * 4];
  uint2v hv, lv;
  split4(w, hv, lv);
  ((uint2v*)Whi)[idx4] = hv;
  ((uint2v*)Wlo)[idx4] = lv;
}

// ---------------- kernel 2: Uh[b][i] = sum_j U[i][j]*hidden[b][j] ----------------
__global__ __launch_bounds__(256) void uh_kernel(const float* __restrict__ U,
                                                 const float* __restrict__ hidden,
                                                 float* __restrict__ Uh) {
  int wid = threadIdx.x >> 6, lane = threadIdx.x & 63;
  int i = blockIdx.x * 4 + wid;
  const float* Urow = U + (size_t)i * HDIM;
  float acc[64];
#pragma unroll
  for (int b = 0; b < 64; ++b) acc[b] = 0.0f;
  for (int t = 0; t < HDIM / 64; ++t) {
    float w = Urow[t * 64 + lane];
#pragma unroll
    for (int b = 0; b < 64; ++b)
      acc[b] += w * hidden[(size_t)b * HDIM + t * 64 + lane];
  }
#pragma unroll
  for (int mask = 1; mask <= 32; mask <<= 1)
#pragma unroll
    for (int b = 0; b < 64; ++b) acc[b] += __shfl_xor(acc[b], mask, 64);
  if (lane == 0) {
#pragma unroll
    for (int b = 0; b < 64; ++b) Uh[(size_t)b * HDIM + i] = acc[b];
  }
}

// ---------------- kernel 3: fused e = v . tanh(W@enc + Uh), BK=32, LDS 41KB ----------------
// grid (8, 256), 4 waves. 3-pass split-bf16 MFMA. Target 3 blocks/CU resident.
__global__ __launch_bounds__(256) void e_kernel(const float* __restrict__ enc,
                                                const ushort_t* __restrict__ Whi,
                                                const ushort_t* __restrict__ Wlo,
                                                const float* __restrict__ Uh,
                                                const float* __restrict__ v,
                                                float* __restrict__ e_parts) {
  __shared__ short Ahi[128 * 40], Alo[128 * 40], Bhi[128 * 40], Blo[128 * 40];
  __shared__ float ewave[2][2][64];

  const int t = threadIdx.x;
  const int i0 = blockIdx.x * 128;   // col chunk in H
  const int bs0 = blockIdx.y * 128;  // row tile in B*S
  const int wid = t >> 6, lane = t & 63, r = lane & 15, g = lane >> 4;
  const int wr = wid >> 1, wc = wid & 1;

  f32x4 z4 = {0.f, 0.f, 0.f, 0.f};
  f32x4 acc[4][4];
#pragma unroll
  for (int m = 0; m < 4; ++m)
#pragma unroll
    for (int n = 0; n < 4; ++n) acc[m][n] = z4;

  for (int kt = 0; kt < 32; ++kt) {
    __syncthreads();
    // stage A (enc rows, f32 -> hi/lo bf16), 128x32
#pragma unroll
    for (int rep = 0; rep < 4; ++rep) {
      int p = rep * 256 + t;
      int row = p >> 3, c = p & 7;
      f32x4 w = *(const f32x4*)&enc[(size_t)(bs0 + row) * HDIM + kt * 32 + c * 4];
      uint2v hv, lv;
      split4(w, hv, lv);
      int idx = row * 40 + c * 4;
      *(uint2v*)&Ahi[idx] = hv;
      *(uint2v*)&Alo[idx] = lv;
    }
    // stage B (precomputed W hi/lo bf16), 128x32
#pragma unroll
    for (int rep = 0; rep < 2; ++rep) {
      int p = rep * 256 + t;
      int row = p >> 2, c = p & 3;
      int idx = row * 40 + c * 8;
      *(uint4v*)&Bhi[idx] = *(const uint4v*)&Whi[(size_t)(i0 + row) * HDIM + kt * 32 + c * 8];
      *(uint4v*)&Blo[idx] = *(const uint4v*)&Wlo[(size_t)(i0 + row) * HDIM + kt * 32 + c * 8];
    }
    __syncthreads();
    {
      int k = g * 8;
      bf16x8 ah[4], al[4], bh[4], bl[4];
#pragma unroll
      for (int m = 0; m < 4; ++m) {
        int arow = wr * 64 + m * 16 + r;
        ah[m] = ldfrag40(Ahi, arow, k);
        al[m] = ldfrag40(Alo, arow, k);
        int brow = wc * 64 + m * 16 + r;
        bh[m] = ldfrag40(Bhi, brow, k);
        bl[m] = ldfrag40(Blo, brow, k);
      }
#pragma unroll
      for (int m = 0; m < 4; ++m)
#pragma unroll
        for (int n = 0; n < 4; ++n) {
          acc[m][n] = MF(ah[m], bh[n], acc[m][n]);
          acc[m][n] = MF(ah[m], bl[n], acc[m][n]);
          acc[m][n] = MF(al[m], bh[n], acc[m][n]);
        }
    }
  }

  // epilogue: e contribution = sum over this block's 128 cols of v[i]*tanh(Wh+Uh)
  const int b = bs0 >> 9;
  float uhv[4], vv[4];
#pragma unroll
  for (int n = 0; n < 4; ++n) {
    int col = i0 + wc * 64 + n * 16 + r;
    uhv[n] = Uh[(size_t)b * HDIM + col];
    vv[n] = v[col];
  }
  float esum[16];
#pragma unroll
  for (int q = 0; q < 16; ++q) esum[q] = 0.0f;
#pragma unroll
  for (int m = 0; m < 4; ++m)
#pragma unroll
    for (int n = 0; n < 4; ++n)
#pragma unroll
      for (int j = 0; j < 4; ++j) {
        float s = acc[m][n][j] + uhv[n];
        esum[m * 4 + j] += fast_tanh(s) * vv[n];
      }
#pragma unroll
  for (int mask = 1; mask <= 8; mask <<= 1)
#pragma unroll
    for (int q = 0; q < 16; ++q) esum[q] += __shfl_xor(esum[q], mask, 64);
  if (r == 0) {
#pragma unroll
    for (int m = 0; m < 4; ++m)
#pragma unroll
      for (int j = 0; j < 4; ++j)
        ewave[wr][wc][m * 16 + g * 4 + j] = esum[m * 4 + j];
  }
  __syncthreads();
  if (t < 128) {
    int w2 = t >> 6, rr = t & 63;
    e_parts[(size_t)blockIdx.x * 32768 + bs0 + w2 * 64 + rr] =
        ewave[w2][0][rr] + ewave[w2][1][rr];
  }
}

// ---------------- kernel 4: softmax over S per b ----------------
__global__ __launch_bounds__(256) void softmax_kernel(const float* __restrict__ e_parts,
                                                      float* __restrict__ alpha) {
  __shared__ float red[256];
  int b = blockIdx.x, t = threadIdx.x;
  float ev0 = 0.f, ev1 = 0.f;
#pragma unroll
  for (int nc = 0; nc < 8; ++nc) {
    ev0 += e_parts[(size_t)nc * 32768 + b * SEQ + t];
    ev1 += e_parts[(size_t)nc * 32768 + b * SEQ + t + 256];
  }
  red[t] = fmaxf(ev0, ev1);
  __syncthreads();
  for (int off = 128; off > 0; off >>= 1) {
    if (t < off) red[t] = fmaxf(red[t], red[t + off]);
    __syncthreads();
  }
  float mx = red[0];
  __syncthreads();
  float x0 = __expf(ev0 - mx), x1 = __expf(ev1 - mx);
  red[t] = x0 + x1;
  __syncthreads();
  for (int off = 128; off > 0; off >>= 1) {
    if (t < off) red[t] += red[t + off];
    __syncthreads();
  }
  float inv = 1.0f / red[0];
  alpha[b * SEQ + t] = x0 * inv;
  alpha[b * SEQ + t + 256] = x1 * inv;
}

// ---------------- kernel 5: context partials, grid (64 b, 4 s-chunk, 4 h-chunk) ----------------
__global__ __launch_bounds__(256) void ctx_kernel(const float* __restrict__ alpha,
                                                  const float* __restrict__ enc,
                                                  float* __restrict__ ctx_parts) {
  int b = blockIdx.x, qs = blockIdx.y, qh = blockIdx.z, t = threadIdx.x;
  int h = qh * 256 + t;
  float a0 = 0.f, a1 = 0.f, a2 = 0.f, a3 = 0.f;
  int s0 = qs * 128;
  for (int s = s0; s < s0 + 128; s += 4) {
    float w0 = alpha[b * SEQ + s + 0];
    float w1 = alpha[b * SEQ + s + 1];
    float w2 = alpha[b * SEQ + s + 2];
    float w3 = alpha[b * SEQ + s + 3];
    a0 += w0 * enc[((size_t)b * SEQ + s + 0) * HDIM + h];
    a1 += w1 * enc[((size_t)b * SEQ + s + 1) * HDIM + h];
    a2 += w2 * enc[((size_t)b * SEQ + s + 2) * HDIM + h];
    a3 += w3 * enc[((size_t)b * SEQ + s + 3) * HDIM + h];
  }
  ctx_parts[((size_t)qs * BATCH + b) * HDIM + h] = (a0 + a1) + (a2 + a3);
}

__global__ __launch_bounds__(256) void ctx_reduce_kernel(const float* __restrict__ ctx_parts,
                                                         float* __restrict__ ctx) {
  int idx = blockIdx.x * 256 + threadIdx.x;  // 16384 float4s = 65536 elems
  const f32x4* p = (const f32x4*)ctx_parts;
  f32x4 s0 = p[idx];
  f32x4 s1 = p[idx + 16384];
  f32x4 s2 = p[idx + 32768];
  f32x4 s3 = p[idx + 49152];
  f32x4 r;
  r.x = s0.x + s1.x + s2.x + s3.x;
  r.y = s0.y + s1.y + s2.y + s3.y;
  r.z = s0.z + s1.z + s2.z + s3.z;
  r.w = s0.w + s1.w + s2.w + s3.w;
  ((f32x4*)ctx)[idx] = r;
}

// ---------------- kernel 6: RNN step ----------------
__global__ __launch_bounds__(256) void rnn_kernel(const int* __restrict__ inp,
                                                  const float* __restrict__ emb,
                                                  const float* __restrict__ Wih,
                                                  const float* __restrict__ Whh,
                                                  const float* __restrict__ bih,
                                                  const float* __restrict__ bhh,
                                                  const float* __restrict__ ctx,
                                                  float* __restrict__ h_out,
                                                  ushort_t* __restrict__ h_bf16) {
  int wid = threadIdx.x >> 6, lane = threadIdx.x & 63;
  int i = blockIdx.x * 4 + wid;
  float acc[64];
#pragma unroll
  for (int b = 0; b < 64; ++b) acc[b] = 0.0f;
  const float* w1 = Wih + (size_t)i * EDIM;
  for (int t = 0; t < EDIM / 64; ++t) {
    float w = w1[t * 64 + lane];
#pragma unroll
    for (int b = 0; b < 64; ++b)
      acc[b] += w * emb[(size_t)inp[b] * EDIM + t * 64 + lane];
  }
  const float* w2 = Whh + (size_t)i * HDIM;
  for (int t = 0; t < HDIM / 64; ++t) {
    float w = w2[t * 64 + lane];
#pragma unroll
    for (int b = 0; b < 64; ++b)
      acc[b] += w * ctx[(size_t)b * HDIM + t * 64 + lane];
  }
#pragma unroll
  for (int mask = 1; mask <= 32; mask <<= 1)
#pragma unroll
    for (int b = 0; b < 64; ++b) acc[b] += __shfl_xor(acc[b], mask, 64);
  if (lane == 0) {
    float bias = bih[i] + bhh[i];
#pragma unroll
    for (int b = 0; b < 64; ++b) {
      float hv = fast_tanh(acc[b] + bias);
      h_out[(size_t)b * HDIM + i] = hv;
      unsigned u = __float_as_uint(hv);
      h_bf16[(size_t)b * HDIM + i] = (ushort_t)((u + 0x7FFFu + ((u >> 16) & 1u)) >> 16);
    }
  }
}

// ---------------- kernel 7: logits, BN=64, grid 786 ----------------
__global__ __launch_bounds__(256) void logits_kernel(const ushort_t* __restrict__ hbf,
                                                     const float* __restrict__ outW,
                                                     const float* __restrict__ outb,
                                                     float* __restrict__ out) {
  __shared__ short As[64 * 64];  // h tile (batch 64 x k 64)
  __shared__ short Bs[64 * 64];  // outW tile (64 cols x k 64)
  const int t = threadIdx.x;
  const int n0 = blockIdx.x * 64;
  const int wid = t >> 6, lane = t & 63, r = lane & 15, g = lane >> 4;

  f32x4 z4 = {0.f, 0.f, 0.f, 0.f};
  f32x4 acc[4];
#pragma unroll
  for (int m = 0; m < 4; ++m) acc[m] = z4;

  for (int kt = 0; kt < 16; ++kt) {
    __syncthreads();
#pragma unroll
    for (int rep = 0; rep < 2; ++rep) {
      int p = rep * 256 + t;
      int row = p >> 3, c = p & 7;
      *(uint4v*)&As[row * 64 + ((c * 8) ^ ((row & 7) << 3))] =
          *(const uint4v*)&hbf[(size_t)row * HDIM + kt * 64 + c * 8];
    }
#pragma unroll
    for (int rep = 0; rep < 4; ++rep) {
      int p = rep * 256 + t;
      int row = p >> 4, c = p & 15;
      int gr = n0 + row;
      f32x4 wv = z4;
      if (gr < VSZ) wv = *(const f32x4*)&outW[(size_t)gr * HDIM + kt * 64 + c * 4];
      *(uint2v*)&Bs[row * 64 + ((c * 4) ^ ((row & 7) << 3))] = packhi4_rn(wv);
    }
    __syncthreads();
#pragma unroll
    for (int ks = 0; ks < 2; ++ks) {
      int k = ks * 32 + g * 8;
      bf16x8 a[4], bb;
#pragma unroll
      for (int m = 0; m < 4; ++m) a[m] = ldfrag(As, m * 16 + r, k);
      bb = ldfrag(Bs, wid * 16 + r, k);
#pragma unroll
      for (int m = 0; m < 4; ++m) acc[m] = MF(a[m], bb, acc[m]);
    }
  }
  {
    int col = n0 + wid * 16 + r;
    if (col < VSZ) {
      float ob = outb[col];
#pragma unroll
      for (int m = 0; m < 4; ++m)
#pragma unroll
        for (int j = 0; j < 4; ++j) {
          int row = m * 16 + g * 4 + j;  // batch index
          out[(size_t)row * VSZ + col] = acc[m][j] + ob;
        }
    }
  }
}

// ---------------- launch ----------------
extern "C" void kernel_launch(void* const* d_in, const int* in_sizes, int n_in,
                              void* d_out, int out_size, void* d_ws, size_t ws_size,
                              hipStream_t stream) {
  const int* inp = (const int*)d_in[0];
  const float* hidden = (const float*)d_in[1];
  const float* enc = (const float*)d_in[2];
  const float* emb = (const float*)d_in[3];
  const float* W = (const float*)d_in[4];
  const float* U = (const float*)d_in[5];
  const float* v = (const float*)d_in[6];
  const float* Wih = (const float*)d_in[7];
  const float* Whh = (const float*)d_in[8];
  const float* bih = (const float*)d_in[9];
  const float* bhh = (const float*)d_in[10];
  const float* outW = (const float*)d_in[11];
  const float* outb = (const float*)d_in[12];
  float* out = (float*)d_out;

  char* ws = (char*)d_ws;
  ushort_t* Whi = (ushort_t*)(ws + 0);              // 2 MB
  ushort_t* Wlo = (ushort_t*)(ws + 2097152);        // 2 MB
  float* Uh = (float*)(ws + 4194304);               // 256 KB
  float* e_parts = (float*)(ws + 4456448);          // 1 MB (8 x 32768)
  float* alpha = (float*)(ws + 5505024);            // 128 KB
  float* ctx_parts = (float*)(ws + 5636096);        // 1 MB (4 x 64 x 1024)
  float* ctx = (float*)(ws + 6684672);              // 256 KB
  ushort_t* hbf = (ushort_t*)(ws + 6946816);        // 128 KB
  // total ws usage: ~7.08 MB (unchanged from the passing baseline)

  prep_w_kernel<<<1024, 256, 0, stream>>>(W, Whi, Wlo);
  uh_kernel<<<256, 256, 0, stream>>>(U, hidden, Uh);
  e_kernel<<<dim3(8, 256), 256, 0, stream>>>(enc, Whi, Wlo, Uh, v, e_parts);
  softmax_kernel<<<64, 256, 0, stream>>>(e_parts, alpha);
  ctx_kernel<<<dim3(64, 4, 4), 256, 0, stream>>>(alpha, enc, ctx_parts);
  ctx_reduce_kernel<<<64, 256, 0, stream>>>(ctx_parts, ctx);
  rnn_kernel<<<256, 256, 0, stream>>>(inp, emb, Wih, Whh, bih, bhh, ctx,
                                      out + (size_t)BATCH * VSZ, hbf);
  logits_kernel<<<(VSZ + 63) / 64, 256, 0, stream>>>(hbf, outW, outb, out);
}